// Round 18
// baseline (117.663 us; speedup 1.0000x reference)
//
#include <hip/hip_runtime.h>

#define N_NODES 50000
#define N_EDGES 800000
#define IN_DIM  128
#define HID_DIM 64
#define OUT_DIM 64
#define NBUCK   196          // bucket b covers nodes [b*256, b*256+256)
#define CAP     6144         // padded slots per bucket (max load ~4400)
#define EPB     8192         // edges per scatter block (2-pass, reg-staged)
#define SCAT_BLOCKS 98       // ceil(800000/8192)
#define GEMM1_BLOCKS 3125    // 50000/16
#define AGG_BLOCKS 3125      // 50000/16
#define SBUF_CAP 6144

typedef _Float16 half4v __attribute__((ext_vector_type(4)));
typedef _Float16 half8v __attribute__((ext_vector_type(8)));
typedef float float4v __attribute__((ext_vector_type(4)));

__device__ __forceinline__ void f4addh(float4& a, const half4v v) {
    a.x += (float)v.x; a.y += (float)v.y; a.z += (float)v.z; a.w += (float)v.w;
}

// ---------------- scatter (2-pass, long runs) || gemm1 (unscaled) -------------------
// ebuf entry: src | dst<<16. bucket = entry>>24 (= dst>>8).
// bcur[b] holds RELATIVE count (memset-0 init); global base = b*CAP + old.
__global__ __launch_bounds__(256) void k_scatter_gemm1(
        const int* __restrict__ src, const int* __restrict__ dst,
        int* __restrict__ bcur, unsigned int* __restrict__ ebuf,
        const float* __restrict__ x, const float* __restrict__ W1,
        _Float16* __restrict__ h1s) {
    __shared__ union {
        struct {
            int histo[256];
            int rank[256];
            int gbase[256];
        } sc;                          // 3 KB (scatter role)
        float xs[16][IN_DIM];          // 8 KB (gemm1 role)
    } sm;
    const int bid = blockIdx.x;
    const int t = threadIdx.x;
    if (bid < SCAT_BLOCKS) {
        const int base = bid * EPB;
        sm.sc.histo[t] = 0;
        sm.sc.rank[t] = 0;
        __syncthreads();
        // ---- pass 1: histogram (dst only) ----
#pragma unroll
        for (int c = 0; c < 4; ++c) {
            const int e0 = base + c * 2048 + t * 8;
            if (e0 + 8 <= N_EDGES) {
                const int4 da = *reinterpret_cast<const int4*>(&dst[e0]);
                const int4 db = *reinterpret_cast<const int4*>(&dst[e0 + 4]);
                atomicAdd(&sm.sc.histo[da.x >> 8], 1);
                atomicAdd(&sm.sc.histo[da.y >> 8], 1);
                atomicAdd(&sm.sc.histo[da.z >> 8], 1);
                atomicAdd(&sm.sc.histo[da.w >> 8], 1);
                atomicAdd(&sm.sc.histo[db.x >> 8], 1);
                atomicAdd(&sm.sc.histo[db.y >> 8], 1);
                atomicAdd(&sm.sc.histo[db.z >> 8], 1);
                atomicAdd(&sm.sc.histo[db.w >> 8], 1);
            }
        }
        __syncthreads();
        {
            const int v = sm.sc.histo[t];
            sm.sc.gbase[t] = t * CAP + ((v > 0) ? atomicAdd(&bcur[t], v) : 0);
        }
        __syncthreads();
        // ---- pass 2: re-read, rank, place (runs of ~42 u32 per bucket) ----
#pragma unroll
        for (int c = 0; c < 4; ++c) {
            const int e0 = base + c * 2048 + t * 8;
            if (e0 + 8 <= N_EDGES) {
                const int4 da = *reinterpret_cast<const int4*>(&dst[e0]);
                const int4 db = *reinterpret_cast<const int4*>(&dst[e0 + 4]);
                const int4 sa = *reinterpret_cast<const int4*>(&src[e0]);
                const int4 sb = *reinterpret_cast<const int4*>(&src[e0 + 4]);
                unsigned u[8];
                u[0] = (unsigned)sa.x | ((unsigned)da.x << 16);
                u[1] = (unsigned)sa.y | ((unsigned)da.y << 16);
                u[2] = (unsigned)sa.z | ((unsigned)da.z << 16);
                u[3] = (unsigned)sa.w | ((unsigned)da.w << 16);
                u[4] = (unsigned)sb.x | ((unsigned)db.x << 16);
                u[5] = (unsigned)sb.y | ((unsigned)db.y << 16);
                u[6] = (unsigned)sb.z | ((unsigned)db.z << 16);
                u[7] = (unsigned)sb.w | ((unsigned)db.w << 16);
#pragma unroll
                for (int j = 0; j < 8; ++j) {
                    const int b = (int)(u[j] >> 24);
                    const int r = atomicAdd(&sm.sc.rank[b], 1);
                    ebuf[sm.sc.gbase[b] + r] = u[j];
                }
            }
        }
        return;
    }
    // ---- gemm1 role: 16 nodes/block, 4 nodes/thread; UNSCALED fp16 out ----
    const int wave = t >> 6;
    const int lane = t & 63;
    const long nb = (long)(bid - SCAT_BLOCKS) * 16;
    {
        float4* xsv = reinterpret_cast<float4*>(&sm.xs[0][0]);
        const float4* xv = reinterpret_cast<const float4*>(&x[nb * IN_DIM]);
        xsv[t]       = xv[t];
        xsv[t + 256] = xv[t + 256];
    }
    __syncthreads();
    const int n0 = wave * 4, n1 = n0 + 1, n2 = n0 + 2, n3 = n0 + 3;
    float a0 = 0.f, a1 = 0.f, a2 = 0.f, a3 = 0.f;
#pragma unroll 8
    for (int k = 0; k < IN_DIM; ++k) {
        const float wv = W1[k * HID_DIM + lane];
        a0 = fmaf(sm.xs[n0][k], wv, a0);
        a1 = fmaf(sm.xs[n1][k], wv, a1);
        a2 = fmaf(sm.xs[n2][k], wv, a2);
        a3 = fmaf(sm.xs[n3][k], wv, a3);
    }
    h1s[(nb + n0) * HID_DIM + lane] = (_Float16)a0;
    h1s[(nb + n1) * HID_DIM + lane] = (_Float16)a1;
    h1s[(nb + n2) * HID_DIM + lane] = (_Float16)a2;
    h1s[(nb + n3) * HID_DIM + lane] = (_Float16)a3;
}

// ---------------- counts + offsets + CSR placement + h1 rescale ----------------
__global__ __launch_bounds__(256) void k_counts_place(
        const unsigned int* __restrict__ ebuf, const int* __restrict__ bcur,
        int* __restrict__ counts, int* __restrict__ offsets,
        unsigned short* __restrict__ csr, _Float16* __restrict__ h1s) {
    __shared__ int cnt[256];
    __shared__ int loff[256];
    __shared__ unsigned short sbuf[SBUF_CAP];
    const int t = threadIdx.x;
    const int nb = blockIdx.x;
    const int beg = nb * CAP;
    const int seglen = bcur[nb];          // relative count
    const int end = beg + seglen;
    cnt[t] = 0;
    __syncthreads();
    for (int e = beg + t; e < end; e += 256)
        atomicAdd(&cnt[(ebuf[e] >> 16) & 255], 1);
    __syncthreads();
    const int v = cnt[t];
    loff[t] = v;
    __syncthreads();
    for (int off = 1; off < 256; off <<= 1) {
        int add = (t >= off) ? loff[t - off] : 0;
        __syncthreads();
        loff[t] += add;
        __syncthreads();
    }
    const int ex = loff[t] - v;
    __syncthreads();
    loff[t] = ex;
    cnt[t] = 0;          // reuse as rank
    const int node = nb * 256 + t;
    float di = 1.0f;
    if (node < N_NODES) {
        counts[node] = v;
        offsets[node] = beg + ex;     // offsets point into padded csr
        di = rsqrtf((float)(v + 1));  // +1: self-loop
    }
    __syncthreads();
    for (int e = beg + t; e < end; e += 256) {
        const unsigned int u = ebuf[e];
        const unsigned short sv = (unsigned short)(u & 0xFFFF);
        const int dl = (int)((u >> 16) & 255);
        const int r = atomicAdd(&cnt[dl], 1);
        sbuf[loff[dl] + r] = sv;
    }
    __syncthreads();
    for (int i = t; i < seglen; i += 256)
        csr[beg + i] = sbuf[i];
    // rescale h1 row by dinv (pre-scaled rows keep the aggs in their fastest form)
    if (node < N_NODES) {
#pragma unroll
        for (int d = 0; d < 8; ++d) {
            half8v hv = *reinterpret_cast<half8v*>(&h1s[(long)node * 64 + d * 8]);
#pragma unroll
            for (int j = 0; j < 8; ++j) hv[j] = (_Float16)((float)hv[j] * di);
            *reinterpret_cast<half8v*>(&h1s[(long)node * 64 + d * 8]) = hv;
        }
    }
}

// ---------------- gather core: nontemporal row loads (skip L1 alloc) -----------------
__device__ __forceinline__ half4v ntload(const _Float16* p) {
    return __builtin_nontemporal_load(reinterpret_cast<const half4v*>(p));
}

__device__ __forceinline__ float4 gather_node(
        const unsigned short* __restrict__ csr, const _Float16* __restrict__ h,
        int n, int beg, int cnt, int sub) {
    float4 a0 = {0,0,0,0}, a1 = {0,0,0,0}, a2 = {0,0,0,0}, a3 = {0,0,0,0};
    int e = 0;
    for (; e + 8 <= cnt; e += 8) {
        int idx[8];
#pragma unroll
        for (int j = 0; j < 8; ++j) idx[j] = csr[beg + e + j];
        half4v v[8];
#pragma unroll
        for (int j = 0; j < 8; ++j)
            v[j] = ntload(&h[(long)idx[j] * 64 + sub * 4]);
        f4addh(a0, v[0]); f4addh(a1, v[1]); f4addh(a2, v[2]); f4addh(a3, v[3]);
        f4addh(a0, v[4]); f4addh(a1, v[5]); f4addh(a2, v[6]); f4addh(a3, v[7]);
    }
    if (e + 4 <= cnt) {
        int idx[4];
#pragma unroll
        for (int j = 0; j < 4; ++j) idx[j] = csr[beg + e + j];
        half4v v[4];
#pragma unroll
        for (int j = 0; j < 4; ++j)
            v[j] = ntload(&h[(long)idx[j] * 64 + sub * 4]);
        f4addh(a0, v[0]); f4addh(a1, v[1]); f4addh(a2, v[2]); f4addh(a3, v[3]);
        e += 4;
    }
    for (; e < cnt; ++e)
        f4addh(a0, ntload(&h[(long)csr[beg + e] * 64 + sub * 4]));
    f4addh(a1, *reinterpret_cast<const half4v*>(&h[(long)n * 64 + sub * 4]));  // self-loop
    float4 a;
    a.x = (a0.x + a1.x) + (a2.x + a3.x);
    a.y = (a0.y + a1.y) + (a2.y + a3.y);
    a.z = (a0.z + a1.z) + (a2.z + a3.z);
    a.w = (a0.w + a1.w) + (a2.w + a3.w);
    return a;
}

// ---------------- fused: agg layer1 + bias + ReLU + GEMM2 + pre-scale ---------------
__global__ __launch_bounds__(256) void k_agg1_fused(
        const unsigned short* __restrict__ csr, const int* __restrict__ offsets,
        const int* __restrict__ counts,
        const _Float16* __restrict__ h1s, const float* __restrict__ b1,
        const float* __restrict__ W2, _Float16* __restrict__ h3s) {
    __shared__ float rs[16][HID_DIM];   // 4 KB
    __shared__ float dis[16];
    const int g = threadIdx.x >> 4;
    const int sub = threadIdx.x & 15;
    const long nbase = (long)blockIdx.x * 16;
    const int n = (int)nbase + g;
    const int beg = offsets[n];
    const int cnt = counts[n];
    float4 a = gather_node(csr, h1s, n, beg, cnt, sub);
    const float di = rsqrtf((float)(cnt + 1));
    if (sub == 0) dis[g] = di;
    const float4 bv = *reinterpret_cast<const float4*>(&b1[sub * 4]);
    float4 r;
    r.x = fmaxf(a.x * di + bv.x, 0.0f);
    r.y = fmaxf(a.y * di + bv.y, 0.0f);
    r.z = fmaxf(a.z * di + bv.z, 0.0f);
    r.w = fmaxf(a.w * di + bv.w, 0.0f);
    *reinterpret_cast<float4*>(&rs[g][sub * 4]) = r;
    __syncthreads();
    // GEMM phase: wave w computes nodes 4w..4w+3, pre-scaled h3 out
    const int wave = threadIdx.x >> 6;
    const int lane = threadIdx.x & 63;
    float acc[4] = {0.f, 0.f, 0.f, 0.f};
#pragma unroll 4
    for (int k = 0; k < HID_DIM; ++k) {
        const float wv = W2[k * OUT_DIM + lane];
#pragma unroll
        for (int m = 0; m < 4; ++m)
            acc[m] = fmaf(rs[wave * 4 + m][k], wv, acc[m]);
    }
#pragma unroll
    for (int m = 0; m < 4; ++m) {
        const long node = nbase + wave * 4 + m;
        h3s[node * 64 + lane] = (_Float16)(acc[m] * dis[wave * 4 + m]);
    }
}

// ---------------- final aggregation (non-temporal dout stores) ----------------------
__global__ __launch_bounds__(256) void k_agg2(
        const unsigned short* __restrict__ csr, const int* __restrict__ offsets,
        const int* __restrict__ counts,
        const _Float16* __restrict__ h3s, const float* __restrict__ b2,
        float* __restrict__ dout) {
    const int g = threadIdx.x >> 4;
    const int sub = threadIdx.x & 15;
    const int n = blockIdx.x * 16 + g;
    const int beg = offsets[n];
    const int cnt = counts[n];
    float4 a = gather_node(csr, h3s, n, beg, cnt, sub);
    const float di = rsqrtf((float)(cnt + 1));
    const float4 bv = *reinterpret_cast<const float4*>(&b2[sub * 4]);
    float4v r;
    r.x = a.x * di + bv.x;
    r.y = a.y * di + bv.y;
    r.z = a.z * di + bv.z;
    r.w = a.w * di + bv.w;
    __builtin_nontemporal_store(r, reinterpret_cast<float4v*>(&dout[(long)n * 64 + sub * 4]));
}

extern "C" void kernel_launch(void* const* d_in, const int* in_sizes, int n_in,
                              void* d_out, int out_size, void* d_ws, size_t ws_size,
                              hipStream_t stream) {
    const float* x  = (const float*)d_in[0];
    const int*   ei = (const int*)d_in[1];          // [2, N_EDGES]
    const float* W1 = (const float*)d_in[2];
    const float* b1 = (const float*)d_in[3];
    const float* W2 = (const float*)d_in[4];
    const float* b2 = (const float*)d_in[5];
    float* dout = (float*)d_out;

    const int* src = ei;
    const int* dst = ei + N_EDGES;

    char* w = (char*)d_ws;
    int*            counts   = (int*)w;            w += 50176 * 4;
    int*            offsets  = (int*)w;            w += 50176 * 4;
    int*            bcur     = (int*)w;            w += 256 * 4;
    unsigned int*   ebuf     = (unsigned int*)w;   w += (long)NBUCK * CAP * 4;
    unsigned short* csr      = (unsigned short*)w; w += (long)NBUCK * CAP * 2;
    _Float16*       h1s      = (_Float16*)w;       w += (long)N_NODES * 64 * 2;
    _Float16*       h3s      = (_Float16*)w;

    hipMemsetAsync(bcur, 0, 256 * 4, stream);      // bcur = relative counts
    k_scatter_gemm1<<<SCAT_BLOCKS + GEMM1_BLOCKS, 256, 0, stream>>>(
        src, dst, bcur, ebuf, x, W1, h1s);
    k_counts_place<<<NBUCK, 256, 0, stream>>>(ebuf, bcur, counts, offsets, csr, h1s);
    k_agg1_fused<<<AGG_BLOCKS, 256, 0, stream>>>(csr, offsets, counts, h1s, b1, W2, h3s);
    k_agg2<<<AGG_BLOCKS, 256, 0, stream>>>(csr, offsets, counts, h3s, b2, dout);
}

// Round 19
// 97.599 us; speedup vs baseline: 1.2056x; 1.2056x over previous
//
#include <hip/hip_runtime.h>

#define N_NODES 50000
#define N_EDGES 800000
#define IN_DIM  128
#define HID_DIM 64
#define OUT_DIM 64
#define NBUCK   196          // bucket b covers nodes [b*256, b*256+256)
#define CAP     6144         // padded slots per bucket (max load ~4400)
#define EPB     8192         // edges per scatter block (2-pass, reg-staged)
#define SCAT_BLOCKS 98       // ceil(800000/8192)
#define GEMM1_BLOCKS 3125    // 50000/16
#define AGG_BLOCKS 3125      // 50000/16
#define SBUF_CAP 6144

typedef _Float16 half4v __attribute__((ext_vector_type(4)));
typedef _Float16 half8v __attribute__((ext_vector_type(8)));
typedef float float4v __attribute__((ext_vector_type(4)));

__device__ __forceinline__ void f4addh(float4& a, const half4v v) {
    a.x += (float)v.x; a.y += (float)v.y; a.z += (float)v.z; a.w += (float)v.w;
}

// ---------------- scatter (2-pass, long runs) || gemm1 (unscaled) -------------------
// ebuf entry: src | dst<<16. bucket = entry>>24 (= dst>>8).
// bcur[b] holds RELATIVE count (memset-0 init); global base = b*CAP + old.
__global__ __launch_bounds__(256) void k_scatter_gemm1(
        const int* __restrict__ src, const int* __restrict__ dst,
        int* __restrict__ bcur, unsigned int* __restrict__ ebuf,
        const float* __restrict__ x, const float* __restrict__ W1,
        _Float16* __restrict__ h1s) {
    __shared__ union {
        struct {
            int histo[256];
            int rank[256];
            int gbase[256];
        } sc;                          // 3 KB (scatter role)
        float xs[16][IN_DIM];          // 8 KB (gemm1 role)
    } sm;
    const int bid = blockIdx.x;
    const int t = threadIdx.x;
    if (bid < SCAT_BLOCKS) {
        const int base = bid * EPB;
        sm.sc.histo[t] = 0;
        sm.sc.rank[t] = 0;
        __syncthreads();
        // ---- pass 1: histogram (dst only) ----
#pragma unroll
        for (int c = 0; c < 4; ++c) {
            const int e0 = base + c * 2048 + t * 8;
            if (e0 + 8 <= N_EDGES) {
                const int4 da = *reinterpret_cast<const int4*>(&dst[e0]);
                const int4 db = *reinterpret_cast<const int4*>(&dst[e0 + 4]);
                atomicAdd(&sm.sc.histo[da.x >> 8], 1);
                atomicAdd(&sm.sc.histo[da.y >> 8], 1);
                atomicAdd(&sm.sc.histo[da.z >> 8], 1);
                atomicAdd(&sm.sc.histo[da.w >> 8], 1);
                atomicAdd(&sm.sc.histo[db.x >> 8], 1);
                atomicAdd(&sm.sc.histo[db.y >> 8], 1);
                atomicAdd(&sm.sc.histo[db.z >> 8], 1);
                atomicAdd(&sm.sc.histo[db.w >> 8], 1);
            }
        }
        __syncthreads();
        {
            const int v = sm.sc.histo[t];
            sm.sc.gbase[t] = t * CAP + ((v > 0) ? atomicAdd(&bcur[t], v) : 0);
        }
        __syncthreads();
        // ---- pass 2: re-read, rank, place (runs of ~42 u32 per bucket) ----
#pragma unroll
        for (int c = 0; c < 4; ++c) {
            const int e0 = base + c * 2048 + t * 8;
            if (e0 + 8 <= N_EDGES) {
                const int4 da = *reinterpret_cast<const int4*>(&dst[e0]);
                const int4 db = *reinterpret_cast<const int4*>(&dst[e0 + 4]);
                const int4 sa = *reinterpret_cast<const int4*>(&src[e0]);
                const int4 sb = *reinterpret_cast<const int4*>(&src[e0 + 4]);
                unsigned u[8];
                u[0] = (unsigned)sa.x | ((unsigned)da.x << 16);
                u[1] = (unsigned)sa.y | ((unsigned)da.y << 16);
                u[2] = (unsigned)sa.z | ((unsigned)da.z << 16);
                u[3] = (unsigned)sa.w | ((unsigned)da.w << 16);
                u[4] = (unsigned)sb.x | ((unsigned)db.x << 16);
                u[5] = (unsigned)sb.y | ((unsigned)db.y << 16);
                u[6] = (unsigned)sb.z | ((unsigned)db.z << 16);
                u[7] = (unsigned)sb.w | ((unsigned)db.w << 16);
#pragma unroll
                for (int j = 0; j < 8; ++j) {
                    const int b = (int)(u[j] >> 24);
                    const int r = atomicAdd(&sm.sc.rank[b], 1);
                    ebuf[sm.sc.gbase[b] + r] = u[j];
                }
            }
        }
        return;
    }
    // ---- gemm1 role: 16 nodes/block, 4 nodes/thread; UNSCALED fp16 out ----
    const int wave = t >> 6;
    const int lane = t & 63;
    const long nb = (long)(bid - SCAT_BLOCKS) * 16;
    {
        float4* xsv = reinterpret_cast<float4*>(&sm.xs[0][0]);
        const float4* xv = reinterpret_cast<const float4*>(&x[nb * IN_DIM]);
        xsv[t]       = xv[t];
        xsv[t + 256] = xv[t + 256];
    }
    __syncthreads();
    const int n0 = wave * 4, n1 = n0 + 1, n2 = n0 + 2, n3 = n0 + 3;
    float a0 = 0.f, a1 = 0.f, a2 = 0.f, a3 = 0.f;
#pragma unroll 8
    for (int k = 0; k < IN_DIM; ++k) {
        const float wv = W1[k * HID_DIM + lane];
        a0 = fmaf(sm.xs[n0][k], wv, a0);
        a1 = fmaf(sm.xs[n1][k], wv, a1);
        a2 = fmaf(sm.xs[n2][k], wv, a2);
        a3 = fmaf(sm.xs[n3][k], wv, a3);
    }
    h1s[(nb + n0) * HID_DIM + lane] = (_Float16)a0;
    h1s[(nb + n1) * HID_DIM + lane] = (_Float16)a1;
    h1s[(nb + n2) * HID_DIM + lane] = (_Float16)a2;
    h1s[(nb + n3) * HID_DIM + lane] = (_Float16)a3;
}

// ---------------- counts + offsets + CSR placement + h1 rescale ----------------
__global__ __launch_bounds__(256) void k_counts_place(
        const unsigned int* __restrict__ ebuf, const int* __restrict__ bcur,
        int* __restrict__ counts, int* __restrict__ offsets,
        unsigned short* __restrict__ csr, _Float16* __restrict__ h1s) {
    __shared__ int cnt[256];
    __shared__ int loff[256];
    __shared__ unsigned short sbuf[SBUF_CAP];
    const int t = threadIdx.x;
    const int nb = blockIdx.x;
    const int beg = nb * CAP;
    const int seglen = bcur[nb];          // relative count
    const int end = beg + seglen;
    cnt[t] = 0;
    __syncthreads();
    for (int e = beg + t; e < end; e += 256)
        atomicAdd(&cnt[(ebuf[e] >> 16) & 255], 1);
    __syncthreads();
    const int v = cnt[t];
    loff[t] = v;
    __syncthreads();
    for (int off = 1; off < 256; off <<= 1) {
        int add = (t >= off) ? loff[t - off] : 0;
        __syncthreads();
        loff[t] += add;
        __syncthreads();
    }
    const int ex = loff[t] - v;
    __syncthreads();
    loff[t] = ex;
    cnt[t] = 0;          // reuse as rank
    const int node = nb * 256 + t;
    float di = 1.0f;
    if (node < N_NODES) {
        counts[node] = v;
        offsets[node] = beg + ex;     // offsets point into padded csr
        di = rsqrtf((float)(v + 1));  // +1: self-loop
    }
    __syncthreads();
    for (int e = beg + t; e < end; e += 256) {
        const unsigned int u = ebuf[e];
        const unsigned short sv = (unsigned short)(u & 0xFFFF);
        const int dl = (int)((u >> 16) & 255);
        const int r = atomicAdd(&cnt[dl], 1);
        sbuf[loff[dl] + r] = sv;
    }
    __syncthreads();
    for (int i = t; i < seglen; i += 256)
        csr[beg + i] = sbuf[i];
    // rescale h1 row by dinv (pre-scaled rows keep the aggs in their fastest form)
    if (node < N_NODES) {
#pragma unroll
        for (int d = 0; d < 8; ++d) {
            half8v hv = *reinterpret_cast<half8v*>(&h1s[(long)node * 64 + d * 8]);
#pragma unroll
            for (int j = 0; j < 8; ++j) hv[j] = (_Float16)((float)hv[j] * di);
            *reinterpret_cast<half8v*>(&h1s[(long)node * 64 + d * 8]) = hv;
        }
    }
}

// ---------------- gather core: one 16-lane group owns one node, 8-deep pipeline ------
__device__ __forceinline__ float4 gather_node(
        const unsigned short* __restrict__ csr, const _Float16* __restrict__ h,
        int n, int beg, int cnt, int sub) {
    float4 a0 = {0,0,0,0}, a1 = {0,0,0,0}, a2 = {0,0,0,0}, a3 = {0,0,0,0};
    int e = 0;
    for (; e + 8 <= cnt; e += 8) {
        int idx[8];
#pragma unroll
        for (int j = 0; j < 8; ++j) idx[j] = csr[beg + e + j];
        half4v v[8];
#pragma unroll
        for (int j = 0; j < 8; ++j)
            v[j] = *reinterpret_cast<const half4v*>(&h[(long)idx[j] * 64 + sub * 4]);
        f4addh(a0, v[0]); f4addh(a1, v[1]); f4addh(a2, v[2]); f4addh(a3, v[3]);
        f4addh(a0, v[4]); f4addh(a1, v[5]); f4addh(a2, v[6]); f4addh(a3, v[7]);
    }
    if (e + 4 <= cnt) {
        int idx[4];
#pragma unroll
        for (int j = 0; j < 4; ++j) idx[j] = csr[beg + e + j];
        half4v v[4];
#pragma unroll
        for (int j = 0; j < 4; ++j)
            v[j] = *reinterpret_cast<const half4v*>(&h[(long)idx[j] * 64 + sub * 4]);
        f4addh(a0, v[0]); f4addh(a1, v[1]); f4addh(a2, v[2]); f4addh(a3, v[3]);
        e += 4;
    }
    for (; e < cnt; ++e)
        f4addh(a0, *reinterpret_cast<const half4v*>(&h[(long)csr[beg + e] * 64 + sub * 4]));
    f4addh(a1, *reinterpret_cast<const half4v*>(&h[(long)n * 64 + sub * 4]));  // self-loop
    float4 a;
    a.x = (a0.x + a1.x) + (a2.x + a3.x);
    a.y = (a0.y + a1.y) + (a2.y + a3.y);
    a.z = (a0.z + a1.z) + (a2.z + a3.z);
    a.w = (a0.w + a1.w) + (a2.w + a3.w);
    return a;
}

// ---------------- fused: agg layer1 + bias + ReLU + GEMM2 + pre-scale ---------------
__global__ __launch_bounds__(256) void k_agg1_fused(
        const unsigned short* __restrict__ csr, const int* __restrict__ offsets,
        const int* __restrict__ counts,
        const _Float16* __restrict__ h1s, const float* __restrict__ b1,
        const float* __restrict__ W2, _Float16* __restrict__ h3s) {
    __shared__ float rs[16][HID_DIM];   // 4 KB
    __shared__ float dis[16];
    const int g = threadIdx.x >> 4;
    const int sub = threadIdx.x & 15;
    const long nbase = (long)blockIdx.x * 16;
    const int n = (int)nbase + g;
    const int beg = offsets[n];
    const int cnt = counts[n];
    float4 a = gather_node(csr, h1s, n, beg, cnt, sub);
    const float di = rsqrtf((float)(cnt + 1));
    if (sub == 0) dis[g] = di;
    const float4 bv = *reinterpret_cast<const float4*>(&b1[sub * 4]);
    float4 r;
    r.x = fmaxf(a.x * di + bv.x, 0.0f);
    r.y = fmaxf(a.y * di + bv.y, 0.0f);
    r.z = fmaxf(a.z * di + bv.z, 0.0f);
    r.w = fmaxf(a.w * di + bv.w, 0.0f);
    *reinterpret_cast<float4*>(&rs[g][sub * 4]) = r;
    __syncthreads();
    // GEMM phase: wave w computes nodes 4w..4w+3, pre-scaled h3 out
    const int wave = threadIdx.x >> 6;
    const int lane = threadIdx.x & 63;
    float acc[4] = {0.f, 0.f, 0.f, 0.f};
#pragma unroll 4
    for (int k = 0; k < HID_DIM; ++k) {
        const float wv = W2[k * OUT_DIM + lane];
#pragma unroll
        for (int m = 0; m < 4; ++m)
            acc[m] = fmaf(rs[wave * 4 + m][k], wv, acc[m]);
    }
#pragma unroll
    for (int m = 0; m < 4; ++m) {
        const long node = nbase + wave * 4 + m;
        h3s[node * 64 + lane] = (_Float16)(acc[m] * dis[wave * 4 + m]);
    }
}

// ---------------- final aggregation (non-temporal dout stores) ----------------------
__global__ __launch_bounds__(256) void k_agg2(
        const unsigned short* __restrict__ csr, const int* __restrict__ offsets,
        const int* __restrict__ counts,
        const _Float16* __restrict__ h3s, const float* __restrict__ b2,
        float* __restrict__ dout) {
    const int g = threadIdx.x >> 4;
    const int sub = threadIdx.x & 15;
    const int n = blockIdx.x * 16 + g;
    const int beg = offsets[n];
    const int cnt = counts[n];
    float4 a = gather_node(csr, h3s, n, beg, cnt, sub);
    const float di = rsqrtf((float)(cnt + 1));
    const float4 bv = *reinterpret_cast<const float4*>(&b2[sub * 4]);
    float4v r;
    r.x = a.x * di + bv.x;
    r.y = a.y * di + bv.y;
    r.z = a.z * di + bv.z;
    r.w = a.w * di + bv.w;
    __builtin_nontemporal_store(r, reinterpret_cast<float4v*>(&dout[(long)n * 64 + sub * 4]));
}

extern "C" void kernel_launch(void* const* d_in, const int* in_sizes, int n_in,
                              void* d_out, int out_size, void* d_ws, size_t ws_size,
                              hipStream_t stream) {
    const float* x  = (const float*)d_in[0];
    const int*   ei = (const int*)d_in[1];          // [2, N_EDGES]
    const float* W1 = (const float*)d_in[2];
    const float* b1 = (const float*)d_in[3];
    const float* W2 = (const float*)d_in[4];
    const float* b2 = (const float*)d_in[5];
    float* dout = (float*)d_out;

    const int* src = ei;
    const int* dst = ei + N_EDGES;

    char* w = (char*)d_ws;
    int*            counts   = (int*)w;            w += 50176 * 4;
    int*            offsets  = (int*)w;            w += 50176 * 4;
    int*            bcur     = (int*)w;            w += 256 * 4;
    unsigned int*   ebuf     = (unsigned int*)w;   w += (long)NBUCK * CAP * 4;
    unsigned short* csr      = (unsigned short*)w; w += (long)NBUCK * CAP * 2;
    _Float16*       h1s      = (_Float16*)w;       w += (long)N_NODES * 64 * 2;
    _Float16*       h3s      = (_Float16*)w;

    hipMemsetAsync(bcur, 0, 256 * 4, stream);      // bcur = relative counts
    k_scatter_gemm1<<<SCAT_BLOCKS + GEMM1_BLOCKS, 256, 0, stream>>>(
        src, dst, bcur, ebuf, x, W1, h1s);
    k_counts_place<<<NBUCK, 256, 0, stream>>>(ebuf, bcur, counts, offsets, csr, h1s);
    k_agg1_fused<<<AGG_BLOCKS, 256, 0, stream>>>(csr, offsets, counts, h1s, b1, W2, h3s);
    k_agg2<<<AGG_BLOCKS, 256, 0, stream>>>(csr, offsets, counts, h3s, b2, dout);
}

// Round 20
// 95.738 us; speedup vs baseline: 1.2290x; 1.0194x over previous
//
#include <hip/hip_runtime.h>

#define N_NODES 50000
#define N_EDGES 800000
#define IN_DIM  128
#define HID_DIM 64
#define OUT_DIM 64
#define NBUCK   196          // bucket b covers nodes [b*256, b*256+256)
#define CAP     6144         // padded slots per bucket (max load ~4400)
#define EPB     8192         // edges per scatter block (2-pass, reg-staged)
#define SCAT_BLOCKS 98       // ceil(800000/8192)
#define GEMM1_BLOCKS 3125    // 50000/16
#define AGG_BLOCKS 3125      // 50000/16 nodes-per-block(16) @128thr
#define SBUF_CAP 6144

typedef _Float16 half4v __attribute__((ext_vector_type(4)));
typedef _Float16 half8v __attribute__((ext_vector_type(8)));
typedef float float4v __attribute__((ext_vector_type(4)));
typedef float float8v __attribute__((ext_vector_type(8)));

__device__ __forceinline__ void f8addh(float8v& a, const half8v v) {
#pragma unroll
    for (int i = 0; i < 8; ++i) a[i] += (float)v[i];
}

// ---------------- scatter (2-pass, long runs) || gemm1 (unscaled) -------------------
// ebuf entry: src | dst<<16. bucket = entry>>24 (= dst>>8).
// bcur[b] holds RELATIVE count (memset-0 init); global base = b*CAP + old.
__global__ __launch_bounds__(256) void k_scatter_gemm1(
        const int* __restrict__ src, const int* __restrict__ dst,
        int* __restrict__ bcur, unsigned int* __restrict__ ebuf,
        const float* __restrict__ x, const float* __restrict__ W1,
        _Float16* __restrict__ h1s) {
    __shared__ union {
        struct {
            int histo[256];
            int rank[256];
            int gbase[256];
        } sc;                          // 3 KB (scatter role)
        float xs[16][IN_DIM];          // 8 KB (gemm1 role)
    } sm;
    const int bid = blockIdx.x;
    const int t = threadIdx.x;
    if (bid < SCAT_BLOCKS) {
        const int base = bid * EPB;
        sm.sc.histo[t] = 0;
        sm.sc.rank[t] = 0;
        __syncthreads();
        // ---- pass 1: histogram (dst only) ----
#pragma unroll
        for (int c = 0; c < 4; ++c) {
            const int e0 = base + c * 2048 + t * 8;
            if (e0 + 8 <= N_EDGES) {
                const int4 da = *reinterpret_cast<const int4*>(&dst[e0]);
                const int4 db = *reinterpret_cast<const int4*>(&dst[e0 + 4]);
                atomicAdd(&sm.sc.histo[da.x >> 8], 1);
                atomicAdd(&sm.sc.histo[da.y >> 8], 1);
                atomicAdd(&sm.sc.histo[da.z >> 8], 1);
                atomicAdd(&sm.sc.histo[da.w >> 8], 1);
                atomicAdd(&sm.sc.histo[db.x >> 8], 1);
                atomicAdd(&sm.sc.histo[db.y >> 8], 1);
                atomicAdd(&sm.sc.histo[db.z >> 8], 1);
                atomicAdd(&sm.sc.histo[db.w >> 8], 1);
            }
        }
        __syncthreads();
        {
            const int v = sm.sc.histo[t];
            sm.sc.gbase[t] = t * CAP + ((v > 0) ? atomicAdd(&bcur[t], v) : 0);
        }
        __syncthreads();
        // ---- pass 2: re-read, rank, place ----
#pragma unroll
        for (int c = 0; c < 4; ++c) {
            const int e0 = base + c * 2048 + t * 8;
            if (e0 + 8 <= N_EDGES) {
                const int4 da = *reinterpret_cast<const int4*>(&dst[e0]);
                const int4 db = *reinterpret_cast<const int4*>(&dst[e0 + 4]);
                const int4 sa = *reinterpret_cast<const int4*>(&src[e0]);
                const int4 sb = *reinterpret_cast<const int4*>(&src[e0 + 4]);
                unsigned u[8];
                u[0] = (unsigned)sa.x | ((unsigned)da.x << 16);
                u[1] = (unsigned)sa.y | ((unsigned)da.y << 16);
                u[2] = (unsigned)sa.z | ((unsigned)da.z << 16);
                u[3] = (unsigned)sa.w | ((unsigned)da.w << 16);
                u[4] = (unsigned)sb.x | ((unsigned)db.x << 16);
                u[5] = (unsigned)sb.y | ((unsigned)db.y << 16);
                u[6] = (unsigned)sb.z | ((unsigned)db.z << 16);
                u[7] = (unsigned)sb.w | ((unsigned)db.w << 16);
#pragma unroll
                for (int j = 0; j < 8; ++j) {
                    const int b = (int)(u[j] >> 24);
                    const int r = atomicAdd(&sm.sc.rank[b], 1);
                    ebuf[sm.sc.gbase[b] + r] = u[j];
                }
            }
        }
        return;
    }
    // ---- gemm1 role: 16 nodes/block, 4 nodes/thread; UNSCALED fp16 out ----
    const int wave = t >> 6;
    const int lane = t & 63;
    const long nb = (long)(bid - SCAT_BLOCKS) * 16;
    {
        float4* xsv = reinterpret_cast<float4*>(&sm.xs[0][0]);
        const float4* xv = reinterpret_cast<const float4*>(&x[nb * IN_DIM]);
        xsv[t]       = xv[t];
        xsv[t + 256] = xv[t + 256];
    }
    __syncthreads();
    const int n0 = wave * 4, n1 = n0 + 1, n2 = n0 + 2, n3 = n0 + 3;
    float a0 = 0.f, a1 = 0.f, a2 = 0.f, a3 = 0.f;
#pragma unroll 8
    for (int k = 0; k < IN_DIM; ++k) {
        const float wv = W1[k * HID_DIM + lane];
        a0 = fmaf(sm.xs[n0][k], wv, a0);
        a1 = fmaf(sm.xs[n1][k], wv, a1);
        a2 = fmaf(sm.xs[n2][k], wv, a2);
        a3 = fmaf(sm.xs[n3][k], wv, a3);
    }
    h1s[(nb + n0) * HID_DIM + lane] = (_Float16)a0;
    h1s[(nb + n1) * HID_DIM + lane] = (_Float16)a1;
    h1s[(nb + n2) * HID_DIM + lane] = (_Float16)a2;
    h1s[(nb + n3) * HID_DIM + lane] = (_Float16)a3;
}

// ---------------- counts + offsets + CSR placement + h1 rescale ----------------
__global__ __launch_bounds__(256) void k_counts_place(
        const unsigned int* __restrict__ ebuf, const int* __restrict__ bcur,
        int* __restrict__ counts, int* __restrict__ offsets,
        unsigned short* __restrict__ csr, _Float16* __restrict__ h1s) {
    __shared__ int cnt[256];
    __shared__ int loff[256];
    __shared__ unsigned short sbuf[SBUF_CAP];
    const int t = threadIdx.x;
    const int nb = blockIdx.x;
    const int beg = nb * CAP;
    const int seglen = bcur[nb];          // relative count
    const int end = beg + seglen;
    cnt[t] = 0;
    __syncthreads();
    for (int e = beg + t; e < end; e += 256)
        atomicAdd(&cnt[(ebuf[e] >> 16) & 255], 1);
    __syncthreads();
    const int v = cnt[t];
    loff[t] = v;
    __syncthreads();
    for (int off = 1; off < 256; off <<= 1) {
        int add = (t >= off) ? loff[t - off] : 0;
        __syncthreads();
        loff[t] += add;
        __syncthreads();
    }
    const int ex = loff[t] - v;
    __syncthreads();
    loff[t] = ex;
    cnt[t] = 0;          // reuse as rank
    const int node = nb * 256 + t;
    float di = 1.0f;
    if (node < N_NODES) {
        counts[node] = v;
        offsets[node] = beg + ex;     // offsets point into padded csr
        di = rsqrtf((float)(v + 1));  // +1: self-loop
    }
    __syncthreads();
    for (int e = beg + t; e < end; e += 256) {
        const unsigned int u = ebuf[e];
        const unsigned short sv = (unsigned short)(u & 0xFFFF);
        const int dl = (int)((u >> 16) & 255);
        const int r = atomicAdd(&cnt[dl], 1);
        sbuf[loff[dl] + r] = sv;
    }
    __syncthreads();
    for (int i = t; i < seglen; i += 256)
        csr[beg + i] = sbuf[i];
    // rescale h1 row by dinv
    if (node < N_NODES) {
#pragma unroll
        for (int d = 0; d < 8; ++d) {
            half8v hv = *reinterpret_cast<half8v*>(&h1s[(long)node * 64 + d * 8]);
#pragma unroll
            for (int j = 0; j < 8; ++j) hv[j] = (_Float16)((float)hv[j] * di);
            *reinterpret_cast<half8v*>(&h1s[(long)node * 64 + d * 8]) = hv;
        }
    }
}

// ---------------- gather core: 8 lanes/node, 16B(half8v)/lane, 8-deep ---------------
__device__ __forceinline__ float8v gather_node8(
        const unsigned short* __restrict__ csr, const _Float16* __restrict__ h,
        int n, int beg, int cnt, int sub) {
    float8v a0 = {0,0,0,0,0,0,0,0}, a1 = a0, a2 = a0, a3 = a0;
    int e = 0;
    for (; e + 8 <= cnt; e += 8) {
        int idx[8];
#pragma unroll
        for (int j = 0; j < 8; ++j) idx[j] = csr[beg + e + j];
        half8v v[8];
#pragma unroll
        for (int j = 0; j < 8; ++j)
            v[j] = *reinterpret_cast<const half8v*>(&h[(long)idx[j] * 64 + sub * 8]);
        f8addh(a0, v[0]); f8addh(a1, v[1]); f8addh(a2, v[2]); f8addh(a3, v[3]);
        f8addh(a0, v[4]); f8addh(a1, v[5]); f8addh(a2, v[6]); f8addh(a3, v[7]);
    }
    if (e + 4 <= cnt) {
        int idx[4];
#pragma unroll
        for (int j = 0; j < 4; ++j) idx[j] = csr[beg + e + j];
        half8v v[4];
#pragma unroll
        for (int j = 0; j < 4; ++j)
            v[j] = *reinterpret_cast<const half8v*>(&h[(long)idx[j] * 64 + sub * 8]);
        f8addh(a0, v[0]); f8addh(a1, v[1]); f8addh(a2, v[2]); f8addh(a3, v[3]);
        e += 4;
    }
    for (; e < cnt; ++e)
        f8addh(a0, *reinterpret_cast<const half8v*>(&h[(long)csr[beg + e] * 64 + sub * 8]));
    f8addh(a1, *reinterpret_cast<const half8v*>(&h[(long)n * 64 + sub * 8]));  // self-loop
#pragma unroll
    for (int i = 0; i < 8; ++i) a0[i] = (a0[i] + a1[i]) + (a2[i] + a3[i]);
    return a0;
}

// ---------------- fused: agg layer1 + bias + ReLU + GEMM2 + pre-scale ---------------
// 128 threads: 16 groups of 8 lanes, one node each.
__global__ __launch_bounds__(128) void k_agg1_fused(
        const unsigned short* __restrict__ csr, const int* __restrict__ offsets,
        const int* __restrict__ counts,
        const _Float16* __restrict__ h1s, const float* __restrict__ b1,
        const float* __restrict__ W2, _Float16* __restrict__ h3s) {
    __shared__ float rs[16][HID_DIM];   // 4 KB
    __shared__ float dis[16];
    const int g = threadIdx.x >> 3;
    const int sub = threadIdx.x & 7;
    const long nbase = (long)blockIdx.x * 16;
    const int n = (int)nbase + g;
    const int beg = offsets[n];
    const int cnt = counts[n];
    float8v a = gather_node8(csr, h1s, n, beg, cnt, sub);
    const float di = rsqrtf((float)(cnt + 1));
    if (sub == 0) dis[g] = di;
    const float4 b_lo = *reinterpret_cast<const float4*>(&b1[sub * 8]);
    const float4 b_hi = *reinterpret_cast<const float4*>(&b1[sub * 8 + 4]);
    float4 r0, r1;
    r0.x = fmaxf(a[0] * di + b_lo.x, 0.0f);
    r0.y = fmaxf(a[1] * di + b_lo.y, 0.0f);
    r0.z = fmaxf(a[2] * di + b_lo.z, 0.0f);
    r0.w = fmaxf(a[3] * di + b_lo.w, 0.0f);
    r1.x = fmaxf(a[4] * di + b_hi.x, 0.0f);
    r1.y = fmaxf(a[5] * di + b_hi.y, 0.0f);
    r1.z = fmaxf(a[6] * di + b_hi.z, 0.0f);
    r1.w = fmaxf(a[7] * di + b_hi.w, 0.0f);
    *reinterpret_cast<float4*>(&rs[g][sub * 8])     = r0;
    *reinterpret_cast<float4*>(&rs[g][sub * 8 + 4]) = r1;
    __syncthreads();
    // GEMM phase: 2 waves, each computes 8 nodes
    const int wave = threadIdx.x >> 6;
    const int lane = threadIdx.x & 63;
    float acc[8] = {0.f, 0.f, 0.f, 0.f, 0.f, 0.f, 0.f, 0.f};
#pragma unroll 4
    for (int k = 0; k < HID_DIM; ++k) {
        const float wv = W2[k * OUT_DIM + lane];
#pragma unroll
        for (int m = 0; m < 8; ++m)
            acc[m] = fmaf(rs[wave * 8 + m][k], wv, acc[m]);
    }
#pragma unroll
    for (int m = 0; m < 8; ++m) {
        const long node = nbase + wave * 8 + m;
        h3s[node * 64 + lane] = (_Float16)(acc[m] * dis[wave * 8 + m]);
    }
}

// ---------------- final aggregation (no LDS, non-temporal dout stores) --------------
__global__ __launch_bounds__(128) void k_agg2(
        const unsigned short* __restrict__ csr, const int* __restrict__ offsets,
        const int* __restrict__ counts,
        const _Float16* __restrict__ h3s, const float* __restrict__ b2,
        float* __restrict__ dout) {
    const int g = threadIdx.x >> 3;
    const int sub = threadIdx.x & 7;
    const int n = blockIdx.x * 16 + g;
    const int beg = offsets[n];
    const int cnt = counts[n];
    float8v a = gather_node8(csr, h3s, n, beg, cnt, sub);
    const float di = rsqrtf((float)(cnt + 1));
    const float4 b_lo = *reinterpret_cast<const float4*>(&b2[sub * 8]);
    const float4 b_hi = *reinterpret_cast<const float4*>(&b2[sub * 8 + 4]);
    float4v r0, r1;
    r0.x = a[0] * di + b_lo.x;
    r0.y = a[1] * di + b_lo.y;
    r0.z = a[2] * di + b_lo.z;
    r0.w = a[3] * di + b_lo.w;
    r1.x = a[4] * di + b_hi.x;
    r1.y = a[5] * di + b_hi.y;
    r1.z = a[6] * di + b_hi.z;
    r1.w = a[7] * di + b_hi.w;
    __builtin_nontemporal_store(r0, reinterpret_cast<float4v*>(&dout[(long)n * 64 + sub * 8]));
    __builtin_nontemporal_store(r1, reinterpret_cast<float4v*>(&dout[(long)n * 64 + sub * 8 + 4]));
}

extern "C" void kernel_launch(void* const* d_in, const int* in_sizes, int n_in,
                              void* d_out, int out_size, void* d_ws, size_t ws_size,
                              hipStream_t stream) {
    const float* x  = (const float*)d_in[0];
    const int*   ei = (const int*)d_in[1];          // [2, N_EDGES]
    const float* W1 = (const float*)d_in[2];
    const float* b1 = (const float*)d_in[3];
    const float* W2 = (const float*)d_in[4];
    const float* b2 = (const float*)d_in[5];
    float* dout = (float*)d_out;

    const int* src = ei;
    const int* dst = ei + N_EDGES;

    char* w = (char*)d_ws;
    int*            counts   = (int*)w;            w += 50176 * 4;
    int*            offsets  = (int*)w;            w += 50176 * 4;
    int*            bcur     = (int*)w;            w += 256 * 4;
    unsigned int*   ebuf     = (unsigned int*)w;   w += (long)NBUCK * CAP * 4;
    unsigned short* csr      = (unsigned short*)w; w += (long)NBUCK * CAP * 2;
    _Float16*       h1s      = (_Float16*)w;       w += (long)N_NODES * 64 * 2;
    _Float16*       h3s      = (_Float16*)w;

    hipMemsetAsync(bcur, 0, 256 * 4, stream);      // bcur = relative counts
    k_scatter_gemm1<<<SCAT_BLOCKS + GEMM1_BLOCKS, 256, 0, stream>>>(
        src, dst, bcur, ebuf, x, W1, h1s);
    k_counts_place<<<NBUCK, 256, 0, stream>>>(ebuf, bcur, counts, offsets, csr, h1s);
    k_agg1_fused<<<AGG_BLOCKS, 128, 0, stream>>>(csr, offsets, counts, h1s, b1, W2, h3s);
    k_agg2<<<AGG_BLOCKS, 128, 0, stream>>>(csr, offsets, counts, h3s, b2, dout);
}